// Round 3
// baseline (7826.277 us; speedup 1.0000x reference)
//
#include <hip/hip_runtime.h>
#include <stdint.h>

typedef unsigned short u16;
typedef unsigned int u32;
typedef unsigned long long u64;
typedef __attribute__((ext_vector_type(8))) short short8;
typedef __attribute__((ext_vector_type(4))) float floatx4;

#define K_IN    4096   // INPUT_SIZE
#define HID     1024   // HIDDEN
#define G4H     4096   // 4*HIDDEN
#define T_STEPS 2048   // WINDOW
#define NWG     128    // scan workgroups; each owns 8 hidden units
#define SPIN_MAX 60000 // watchdog sweeps; then thread runs free (wrong > hung)

__device__ __forceinline__ u16 f2bf(float f) {
  union { float f; unsigned int i; } v; v.f = f;
  unsigned int lsb = (v.i >> 16) & 1u;
  v.i += 0x7fffu + lsb;
  return (u16)(v.i >> 16);
}
// NaN/Inf -> 0 via INTEGER exponent test: immune to fast-math folding.
__device__ __forceinline__ float finz(float x) {
  unsigned b = __float_as_uint(x);
  return ((b & 0x7f800000u) == 0x7f800000u) ? 0.f : x;
}
__device__ __forceinline__ float sigm(float x) {
  x = fminf(30.f, fmaxf(-30.f, finz(x)));
  return 1.0f / (1.0f + __expf(-x));
}
__device__ __forceinline__ float tanh_s(float x) {
  x = fminf(15.f, fmaxf(-15.f, finz(x)));
  float e = __expf(2.0f * x);
  return (e - 1.0f) / (e + 1.0f);
}

// tagged publish: slot s entry = ((s+1)<<32) | f32bits(h). poison 0xAAAAAAAA never matches.
__device__ __forceinline__ void publish_h(u64* hx, int slot, int idx, float h) {
  h = finz(h);
  u64 v = ((u64)(unsigned)(slot + 1) << 32) | (u64)__float_as_uint(h);
  __hip_atomic_store(&hx[(size_t)slot * HID + idx], v,
                     __ATOMIC_RELAXED, __HIP_MEMORY_SCOPE_AGENT);
}

// poll 2 consecutive entries of slot for tag (slot+1); watchdog -> dead thread.
// R0-proven form (s_sleep throttle). Post-flag this is a one-shot in practice;
// the retry loop remains as the correctness net for flag/data visibility skew.
__device__ __forceinline__ void poll2(const u64* hx, int slot, int j0,
                                      float* v, int* alive) {
  const u64* p = hx + (size_t)slot * HID + j0;
  const unsigned tag = (unsigned)(slot + 1);
  if (*alive) {
    int spins = 0;
    for (;;) {
      u64 a = __hip_atomic_load(&p[0], __ATOMIC_RELAXED, __HIP_MEMORY_SCOPE_AGENT);
      u64 b = __hip_atomic_load(&p[1], __ATOMIC_RELAXED, __HIP_MEMORY_SCOPE_AGENT);
      if ((unsigned)(a >> 32) == tag && (unsigned)(b >> 32) == tag) {
        v[0] = finz(__uint_as_float((unsigned)a));
        v[1] = finz(__uint_as_float((unsigned)b));
        return;
      }
      if (++spins > SPIN_MAX) { *alive = 0; break; }
      __builtin_amdgcn_s_sleep(1);
    }
  }
  v[0] = v[1] = 0.f;
}

// spin on one done-flag (value slot+1). Only 128 threads/WG run this ->
// steady-state poll traffic is 8 lines/WG/sweep instead of 128 (16x cut).
__device__ __forceinline__ void flag_wait(const u32* flags, int slot, int i,
                                          int* alive) {
  const u32* p = flags + (size_t)slot * NWG + i;
  const unsigned tag = (unsigned)(slot + 1);
  if (*alive) {
    int spins = 0;
    while (__hip_atomic_load(p, __ATOMIC_RELAXED, __HIP_MEMORY_SCOPE_AGENT) != tag) {
      if (++spins > SPIN_MAX) { *alive = 0; break; }
      __builtin_amdgcn_s_sleep(1);
    }
  }
}

// ---------------------------------------------------------------------------
// Phase 0: f32 -> bf16 conversion
// ---------------------------------------------------------------------------
__global__ __launch_bounds__(256) void cvt_bf16_k(const float* __restrict__ src,
                                                  u16* __restrict__ dst, int n4) {
  int i = blockIdx.x * 256 + threadIdx.x;
  if (i < n4) {
    float4 v = *(const float4*)(src + (size_t)i * 4);
    u16 o0 = f2bf(v.x), o1 = f2bf(v.y), o2 = f2bf(v.z), o3 = f2bf(v.w);
    ushort4 o = {o0, o1, o2, o3};
    *(ushort4*)(dst + (size_t)i * 4) = o;
  }
}

// ---------------------------------------------------------------------------
// Phase 1: xg = inp @ W_ih^T + b_ih (f32 out). 128x128 tile, BK=64, bf16 MFMA.
// ---------------------------------------------------------------------------
__global__ __launch_bounds__(256) void xg_gemm_k(const u16* __restrict__ A,      // [2048,4096] bf16
                                                 const u16* __restrict__ B,      // [4096,4096] bf16
                                                 const float* __restrict__ bias, // [4096] f32
                                                 float* __restrict__ C)          // [2048,4096] f32
{
  __shared__ __align__(16) u16 As[128 * 64];
  __shared__ __align__(16) u16 Bs[128 * 64];
  const int tid  = threadIdx.x;
  const int lane = tid & 63;
  const int quad = lane >> 4;
  const int l16  = lane & 15;
  const int wid  = tid >> 6;
  const int wm   = wid >> 1, wn = wid & 1;
  const int tileM = blockIdx.y * 128;
  const int tileN = blockIdx.x * 128;

  floatx4 acc[4][4];
  #pragma unroll
  for (int mi = 0; mi < 4; ++mi)
    #pragma unroll
    for (int ni = 0; ni < 4; ++ni)
      acc[mi][ni] = (floatx4){0.f, 0.f, 0.f, 0.f};

  for (int k0 = 0; k0 < K_IN; k0 += 64) {
    #pragma unroll
    for (int i = 0; i < 4; ++i) {
      int c = i * 256 + tid;
      int row = c >> 3, col = (c & 7) * 8;
      *(short8*)(As + c * 8) = *(const short8*)(A + (size_t)(tileM + row) * K_IN + k0 + col);
      *(short8*)(Bs + c * 8) = *(const short8*)(B + (size_t)(tileN + row) * K_IN + k0 + col);
    }
    __syncthreads();
    #pragma unroll
    for (int kk = 0; kk < 64; kk += 32) {
      short8 av[4], bv[4];
      #pragma unroll
      for (int mi = 0; mi < 4; ++mi)
        av[mi] = *(const short8*)(As + (wm * 64 + mi * 16 + l16) * 64 + kk + quad * 8);
      #pragma unroll
      for (int ni = 0; ni < 4; ++ni)
        bv[ni] = *(const short8*)(Bs + (wn * 64 + ni * 16 + l16) * 64 + kk + quad * 8);
      #pragma unroll
      for (int mi = 0; mi < 4; ++mi)
        #pragma unroll
        for (int ni = 0; ni < 4; ++ni)
          acc[mi][ni] = __builtin_amdgcn_mfma_f32_16x16x32_bf16(av[mi], bv[ni], acc[mi][ni], 0, 0, 0);
    }
    __syncthreads();
  }
  #pragma unroll
  for (int ni = 0; ni < 4; ++ni) {
    int n = tileN + wn * 64 + ni * 16 + l16;
    float bn = bias[n];
    #pragma unroll
    for (int mi = 0; mi < 4; ++mi) {
      int mbase = tileM + wm * 64 + mi * 16 + quad * 4;
      #pragma unroll
      for (int r = 0; r < 4; ++r)
        C[(size_t)(mbase + r) * G4H + n] = acc[mi][ni][r] + bn;
    }
  }
}

// ---------------------------------------------------------------------------
// Phase 2: persistent scan. Communication per step:
//   producer g: tid<8 -> ONE coalesced 64B tagged h publish, then tid0 sets
//               flags[t+1][g] (8 cache lines of flags per step, device-wide).
//   consumer:   tid<128 spin (s_sleep) on one flag each -> barrier gates all ->
//               one-shot tagged poll2 of 2 entries/thread (retry = safety net)
//               -> stage LDS -> barrier -> dot (b128+DPP, R2) -> gates.
// Rationale: R0/R2 A/B showed detection latency RISES with poll pressure
// (R2 no-sleep pipelined poll: +8% dur, +15MB FETCH). Flags cut steady-state
// poll traffic ~16x; data is fetched once, when known ready.
// ---------------------------------------------------------------------------
__global__ __launch_bounds__(512, 1) void lstm_scan_k(const float* __restrict__ Whh,
                                                      const float* __restrict__ bhh,
                                                      const float* __restrict__ h1,
                                                      const float* __restrict__ c1,
                                                      const float* __restrict__ fcw,
                                                      const float* __restrict__ fcb,
                                                      const float* __restrict__ xg,
                                                      u64* hx,        // [T_STEPS+1][1024]
                                                      u32* flags,     // [T_STEPS+1][NWG]
                                                      float* out)     // [2080] f32
{
  const int g    = blockIdx.x;
  const int tid  = threadIdx.x;
  const int lane = tid & 63;
  const int w    = tid >> 6;           // wave 0..7
  const int u    = g * 8 + w;          // hidden unit owned by this wave (dot phase)

  __shared__ __align__(16) float h_local[HID];
  __shared__ float gsum2[32];          // [w*4 + q]
  __shared__ float xgb[2][32];         // parity double-buffer, [q*8 + unit]
  __shared__ float bhhb[32];           // [q*8 + unit]
  __shared__ float pp[32][16];

  // W_hh rows {u, H+u, 2H+u, 3H+u} -> VGPRs, laid out for float4 LDS reads:
  // wreg[q][j][k] multiplies h[j*256 + lane*4 + k]
  floatx4 wreg[4][4];
  #pragma unroll
  for (int q = 0; q < 4; ++q) {
    const float* wr = Whh + (size_t)(q * HID + u) * HID;
    #pragma unroll
    for (int j = 0; j < 4; ++j)
      wreg[q][j] = *(const floatx4*)(wr + j * 256 + lane * 4);
  }
  if (tid < 32) bhhb[tid] = bhh[(tid >> 3) * HID + g * 8 + (tid & 7)];

  float c_state = 0.f;
  if (tid < 8) {
    c_state = c1[g * 8 + tid];
    publish_h(hx, 0, g * 8 + tid, h1[g * 8 + tid]);
  }
  if (tid == 0)
    __hip_atomic_store(&flags[g], 1u, __ATOMIC_RELAXED, __HIP_MEMORY_SCOPE_AGENT);

  int alive = 1;
  const int j0 = tid * 2;              // 512 threads x 2 entries = 1024
  for (int t = 0; t < T_STEPS; ++t) {
    float xval = 0.f;                  // issue xg load before flag wait (hides latency)
    if (tid < 32) xval = finz(xg[(size_t)t * G4H + (tid >> 3) * HID + g * 8 + (tid & 7)]);

    if (tid < NWG) flag_wait(flags, t, tid, &alive);
    __syncthreads();                   // gate all 512 threads on readiness

    float v[2];
    poll2(hx, t, j0, v, &alive);       // one-shot in practice
    h_local[j0 + 0] = v[0]; h_local[j0 + 1] = v[1];
    if (tid < 32) xgb[t & 1][tid] = xval;
    __syncthreads();

    // dot: wave w computes the 4 gate rows of unit u via float4 LDS reads
    float s0 = 0.f, s1 = 0.f, s2 = 0.f, s3 = 0.f;
    #pragma unroll
    for (int j = 0; j < 4; ++j) {
      floatx4 hv = *(const floatx4*)(h_local + j * 256 + lane * 4);
      #pragma unroll
      for (int k = 0; k < 4; ++k) {
        s0 = fmaf(wreg[0][j][k], hv[k], s0);
        s1 = fmaf(wreg[1][j][k], hv[k], s1);
        s2 = fmaf(wreg[2][j][k], hv[k], s2);
        s3 = fmaf(wreg[3][j][k], hv[k], s3);
      }
    }

    // full-wave DPP reduction (rocPRIM sequence); totals -> lane 63
#define DPP_LEVEL(mods) \
    asm("v_add_f32 %0, %0, %0 " mods : "+v"(s0)); \
    asm("v_add_f32 %0, %0, %0 " mods : "+v"(s1)); \
    asm("v_add_f32 %0, %0, %0 " mods : "+v"(s2)); \
    asm("v_add_f32 %0, %0, %0 " mods : "+v"(s3));
    DPP_LEVEL("row_shr:1 bound_ctrl:0")
    DPP_LEVEL("row_shr:2 bound_ctrl:0")
    DPP_LEVEL("row_shr:4 bank_mask:0xe")
    DPP_LEVEL("row_shr:8 bank_mask:0xc")
    DPP_LEVEL("row_bcast:15 row_mask:0xa")
    DPP_LEVEL("row_bcast:31 row_mask:0xc")
#undef DPP_LEVEL
    if (lane == 63) {
      gsum2[w * 4 + 0] = s0;
      gsum2[w * 4 + 1] = s1;
      gsum2[w * 4 + 2] = s2;
      gsum2[w * 4 + 3] = s3;
    }
    __syncthreads();

    // gate math + coalesced publish: 8 adjacent threads of wave 0 -> ONE 64B store.
    if (tid < 8) {
      const int uu = tid;
      const float* xb = xgb[t & 1];
      float gi = gsum2[uu * 4 + 0] + xb[uu]      + bhhb[uu];
      float gf = gsum2[uu * 4 + 1] + xb[8 + uu]  + bhhb[8 + uu];
      float gg = gsum2[uu * 4 + 2] + xb[16 + uu] + bhhb[16 + uu];
      float go = gsum2[uu * 4 + 3] + xb[24 + uu] + bhhb[24 + uu];
      float iv = sigm(gi), fv = sigm(gf), gv = tanh_s(gg), ov = sigm(go);
      c_state = finz(fv * c_state + iv * gv);
      float hval = ov * tanh_s(c_state);
      publish_h(hx, t + 1, g * 8 + uu, hval);
      if (t == 1023) {                 // hs[STRIDE-1], cs[STRIDE-1]
        out[32 + g * 8 + uu]       = finz(hval);
        out[32 + HID + g * 8 + uu] = finz(c_state);
      }
    }
    if (tid == 0)
      __hip_atomic_store(&flags[(size_t)(t + 1) * NWG + g], (unsigned)(t + 2),
                         __ATOMIC_RELAXED, __HIP_MEMORY_SCOPE_AGENT);
  }

  // out[0:32] = tanh(h_fin @ fc_w^T + fc_b): block 0 only
  if (g == 0) {
    float v[2];
    poll2(hx, T_STEPS, j0, v, &alive);
    h_local[j0 + 0] = v[0]; h_local[j0 + 1] = v[1];
    __syncthreads();
    const int m = tid >> 4, seg = tid & 15;   // 32 rows x 16 partials of 64
    float pacc = 0.f;
    for (int k = seg * 64; k < seg * 64 + 64; ++k)
      pacc = fmaf(fcw[m * HID + k], h_local[k], pacc);
    pp[m][seg] = finz(pacc);
    __syncthreads();
    if (tid < 32) {
      float sum = fcb[tid];
      #pragma unroll
      for (int i = 0; i < 16; ++i) sum += pp[tid][i];
      out[tid] = tanh_s(finz(sum));
    }
  }
}

extern "C" void kernel_launch(void* const* d_in, const int* in_sizes, int n_in,
                              void* d_out, int out_size, void* d_ws, size_t ws_size,
                              hipStream_t stream) {
  const float* inp = (const float*)d_in[0];
  const float* h1  = (const float*)d_in[1];
  const float* c1  = (const float*)d_in[2];
  const float* Wih = (const float*)d_in[3];
  const float* Whh = (const float*)d_in[4];
  const float* bih = (const float*)d_in[5];
  const float* bhh = (const float*)d_in[6];
  const float* fcw = (const float*)d_in[7];
  const float* fcb = (const float*)d_in[8];
  float* out = (float*)d_out;

  const size_t xg_bytes  = (size_t)T_STEPS * G4H * 4;             // 33.5 MB
  const size_t hx_bytes  = (size_t)(T_STEPS + 1) * HID * 8;       // 16.8 MB
  const size_t ab_bytes  = (size_t)T_STEPS * K_IN * 2;            // 16.8 MB
  const size_t wb_bytes  = (size_t)G4H * K_IN * 2;                // 33.5 MB
  if (ws_size < xg_bytes + hx_bytes + ab_bytes + wb_bytes) return;

  float* xg   = (float*)d_ws;
  u64*   hx   = (u64*)((char*)d_ws + xg_bytes);
  u16*   Abf  = (u16*)((char*)d_ws + xg_bytes + hx_bytes);
  u16*   Wbf  = (u16*)((char*)d_ws + xg_bytes + hx_bytes + ab_bytes);
  // flags alias the FRONT of Abf: Abf is dead once xg_gemm_k completes (same
  // stream => sequential), and (T+1)*128*4 = 1.05MB << 16.8MB. Leftover bf16
  // pairs can't equal a tag t+1<=2049 (needs exact +0.0 bf16 in the high u16);
  // harness poison 0xAAAAAAAA can't either. No init required.
  u32*   flags = (u32*)Abf;

  const int nA4 = T_STEPS * K_IN / 4;
  const int nW4 = G4H * K_IN / 4;
  cvt_bf16_k<<<dim3((nA4 + 255) / 256), 256, 0, stream>>>(inp, Abf, nA4);
  cvt_bf16_k<<<dim3((nW4 + 255) / 256), 256, 0, stream>>>(Wih, Wbf, nW4);
  xg_gemm_k<<<dim3(G4H / 128, T_STEPS / 128), 256, 0, stream>>>(Abf, Wbf, bih, xg);
  lstm_scan_k<<<dim3(NWG), 512, 0, stream>>>(Whh, bhh, h1, c1, fcw, fcb, xg, hx, flags, out);
}

// Round 4
// 4786.695 us; speedup vs baseline: 1.6350x; 1.6350x over previous
//
#include <hip/hip_runtime.h>
#include <stdint.h>

typedef unsigned short u16;
typedef unsigned long long u64;
typedef __attribute__((ext_vector_type(8))) short short8;
typedef __attribute__((ext_vector_type(4))) float floatx4;

#define K_IN    4096   // INPUT_SIZE
#define HID     1024   // HIDDEN
#define G4H     4096   // 4*HIDDEN
#define T_STEPS 2048   // WINDOW
#define NWG     128    // scan workgroups; each owns 8 hidden units
#define SPIN_MAX 60000 // watchdog sweeps; then thread runs free (wrong > hung)

__device__ __forceinline__ u16 f2bf(float f) {
  union { float f; unsigned int i; } v; v.f = f;
  unsigned int lsb = (v.i >> 16) & 1u;
  v.i += 0x7fffu + lsb;
  return (u16)(v.i >> 16);
}
// NaN/Inf -> 0 via INTEGER exponent test: immune to fast-math folding.
__device__ __forceinline__ float finz(float x) {
  unsigned b = __float_as_uint(x);
  return ((b & 0x7f800000u) == 0x7f800000u) ? 0.f : x;
}
__device__ __forceinline__ float sigm(float x) {
  x = fminf(30.f, fmaxf(-30.f, finz(x)));
  return 1.0f / (1.0f + __expf(-x));
}
__device__ __forceinline__ float tanh_s(float x) {
  x = fminf(15.f, fmaxf(-15.f, finz(x)));
  float e = __expf(2.0f * x);
  return (e - 1.0f) / (e + 1.0f);
}

// tagged publish: slot s entry = ((s+1)<<32) | f32bits(h). poison 0xAAAAAAAA never matches.
__device__ __forceinline__ void publish_h(u64* hx, int slot, int idx, float h) {
  h = finz(h);
  u64 v = ((u64)(unsigned)(slot + 1) << 32) | (u64)__float_as_uint(h);
  __hip_atomic_store(&hx[(size_t)slot * HID + idx], v,
                     __ATOMIC_RELAXED, __HIP_MEMORY_SCOPE_AGENT);
}

// poll 2 consecutive entries of slot for tag (slot+1); watchdog -> dead thread.
// R0-proven form: freshest-value load->check->s_sleep(1). A/B history:
//   R2 (3-deep pipelined, no sleep): +370us (stale detection window)
//   R3 (flag gating, extra serial hop): +3000us
// DO NOT TOUCH.
__device__ __forceinline__ void poll2(const u64* hx, int slot, int j0,
                                      float* v, int* alive) {
  const u64* p = hx + (size_t)slot * HID + j0;
  const unsigned tag = (unsigned)(slot + 1);
  if (*alive) {
    int spins = 0;
    for (;;) {
      u64 a = __hip_atomic_load(&p[0], __ATOMIC_RELAXED, __HIP_MEMORY_SCOPE_AGENT);
      u64 b = __hip_atomic_load(&p[1], __ATOMIC_RELAXED, __HIP_MEMORY_SCOPE_AGENT);
      if ((unsigned)(a >> 32) == tag && (unsigned)(b >> 32) == tag) {
        v[0] = finz(__uint_as_float((unsigned)a));
        v[1] = finz(__uint_as_float((unsigned)b));
        return;
      }
      if (++spins > SPIN_MAX) { *alive = 0; break; }
      __builtin_amdgcn_s_sleep(1);
    }
  }
  v[0] = v[1] = 0.f;
}

// ---------------------------------------------------------------------------
// Phase 0: f32 -> bf16 conversion
// ---------------------------------------------------------------------------
__global__ __launch_bounds__(256) void cvt_bf16_k(const float* __restrict__ src,
                                                  u16* __restrict__ dst, int n4) {
  int i = blockIdx.x * 256 + threadIdx.x;
  if (i < n4) {
    float4 v = *(const float4*)(src + (size_t)i * 4);
    u16 o0 = f2bf(v.x), o1 = f2bf(v.y), o2 = f2bf(v.z), o3 = f2bf(v.w);
    ushort4 o = {o0, o1, o2, o3};
    *(ushort4*)(dst + (size_t)i * 4) = o;
  }
}

// ---------------------------------------------------------------------------
// Phase 1: xg = inp @ W_ih^T + b_ih (f32 out). 128x128 tile, BK=64, bf16 MFMA.
// ---------------------------------------------------------------------------
__global__ __launch_bounds__(256) void xg_gemm_k(const u16* __restrict__ A,      // [2048,4096] bf16
                                                 const u16* __restrict__ B,      // [4096,4096] bf16
                                                 const float* __restrict__ bias, // [4096] f32
                                                 float* __restrict__ C)          // [2048,4096] f32
{
  __shared__ __align__(16) u16 As[128 * 64];
  __shared__ __align__(16) u16 Bs[128 * 64];
  const int tid  = threadIdx.x;
  const int lane = tid & 63;
  const int quad = lane >> 4;
  const int l16  = lane & 15;
  const int wid  = tid >> 6;
  const int wm   = wid >> 1, wn = wid & 1;
  const int tileM = blockIdx.y * 128;
  const int tileN = blockIdx.x * 128;

  floatx4 acc[4][4];
  #pragma unroll
  for (int mi = 0; mi < 4; ++mi)
    #pragma unroll
    for (int ni = 0; ni < 4; ++ni)
      acc[mi][ni] = (floatx4){0.f, 0.f, 0.f, 0.f};

  for (int k0 = 0; k0 < K_IN; k0 += 64) {
    #pragma unroll
    for (int i = 0; i < 4; ++i) {
      int c = i * 256 + tid;
      int row = c >> 3, col = (c & 7) * 8;
      *(short8*)(As + c * 8) = *(const short8*)(A + (size_t)(tileM + row) * K_IN + k0 + col);
      *(short8*)(Bs + c * 8) = *(const short8*)(B + (size_t)(tileN + row) * K_IN + k0 + col);
    }
    __syncthreads();
    #pragma unroll
    for (int kk = 0; kk < 64; kk += 32) {
      short8 av[4], bv[4];
      #pragma unroll
      for (int mi = 0; mi < 4; ++mi)
        av[mi] = *(const short8*)(As + (wm * 64 + mi * 16 + l16) * 64 + kk + quad * 8);
      #pragma unroll
      for (int ni = 0; ni < 4; ++ni)
        bv[ni] = *(const short8*)(Bs + (wn * 64 + ni * 16 + l16) * 64 + kk + quad * 8);
      #pragma unroll
      for (int mi = 0; mi < 4; ++mi)
        #pragma unroll
        for (int ni = 0; ni < 4; ++ni)
          acc[mi][ni] = __builtin_amdgcn_mfma_f32_16x16x32_bf16(av[mi], bv[ni], acc[mi][ni], 0, 0, 0);
    }
    __syncthreads();
  }
  #pragma unroll
  for (int ni = 0; ni < 4; ++ni) {
    int n = tileN + wn * 64 + ni * 16 + l16;
    float bn = bias[n];
    #pragma unroll
    for (int mi = 0; mi < 4; ++mi) {
      int mbase = tileM + wm * 64 + mi * 16 + quad * 4;
      #pragma unroll
      for (int r = 0; r < 4; ++r)
        C[(size_t)(mbase + r) * G4H + n] = acc[mi][ni][r] + bn;
    }
  }
}

// ---------------------------------------------------------------------------
// Phase 2: persistent scan. Communication = R0 skeleton, byte-identical:
//   512 threads poll2(2 entries, s_sleep) -> stage LDS -> barrier ->
//   ... -> barrier -> tid<8 ONE coalesced 64B tagged publish.
// R4 shortens only the serial tail between barriers:
//   - dot: 4x ds_read_b128 + 64 fma per wave (one unit/wave)
//   - DPP reduce on VALU pipe (proven R1/R2) -> totals in lane 63
//   - gate math PRE-barrier, in lane 63 of each wave (parallel across waves);
//     hval -> hpub[w] in LDS. Post-barrier path = 1 LDS read + publish only.
// ---------------------------------------------------------------------------
__global__ __launch_bounds__(512, 1) void lstm_scan_k(const float* __restrict__ Whh,
                                                      const float* __restrict__ bhh,
                                                      const float* __restrict__ h1,
                                                      const float* __restrict__ c1,
                                                      const float* __restrict__ fcw,
                                                      const float* __restrict__ fcb,
                                                      const float* __restrict__ xg,
                                                      u64* hx,        // [T_STEPS+1][1024]
                                                      float* out)     // [2080] f32
{
  const int g    = blockIdx.x;
  const int tid  = threadIdx.x;
  const int lane = tid & 63;
  const int w    = tid >> 6;           // wave 0..7
  const int u    = g * 8 + w;          // hidden unit owned by this wave

  __shared__ __align__(16) float h_local[HID];
  __shared__ float hpub[8];            // lane63(w) -> hpub[w]; tid<8 publishes
  __shared__ float xgb[2][32];         // parity double-buffer, [q*8 + unit]
  __shared__ float pp[32][16];

  // W_hh rows {u, H+u, 2H+u, 3H+u} -> VGPRs for float4 LDS dot:
  // wreg[q][j][k] multiplies h[j*256 + lane*4 + k]
  floatx4 wreg[4][4];
  #pragma unroll
  for (int q = 0; q < 4; ++q) {
    const float* wr = Whh + (size_t)(q * HID + u) * HID;
    #pragma unroll
    for (int j = 0; j < 4; ++j)
      wreg[q][j] = *(const floatx4*)(wr + j * 256 + lane * 4);
  }
  // per-wave biases (wave-uniform scalar loads)
  const float bh0 = bhh[u], bh1 = bhh[HID + u], bh2 = bhh[2 * HID + u], bh3 = bhh[3 * HID + u];

  float c_state = c1[u];               // evolves meaningfully in lane 63 only
  if (tid < 8) publish_h(hx, 0, g * 8 + tid, h1[g * 8 + tid]);

  int alive = 1;
  const int j0 = tid * 2;              // 512 threads x 2 entries = 1024
  for (int t = 0; t < T_STEPS; ++t) {
    float xval = 0.f;                  // issue xg load before polling
    if (tid < 32) xval = finz(xg[(size_t)t * G4H + (tid >> 3) * HID + g * 8 + (tid & 7)]);
    float v[2];
    poll2(hx, t, j0, v, &alive);
    h_local[j0 + 0] = v[0]; h_local[j0 + 1] = v[1];
    if (tid < 32) xgb[t & 1][tid] = xval;
    __syncthreads();

    // dot: wave w computes the 4 gate rows of unit u via float4 LDS reads
    float s0 = 0.f, s1 = 0.f, s2 = 0.f, s3 = 0.f;
    #pragma unroll
    for (int j = 0; j < 4; ++j) {
      floatx4 hv = *(const floatx4*)(h_local + j * 256 + lane * 4);
      #pragma unroll
      for (int k = 0; k < 4; ++k) {
        s0 = fmaf(wreg[0][j][k], hv[k], s0);
        s1 = fmaf(wreg[1][j][k], hv[k], s1);
        s2 = fmaf(wreg[2][j][k], hv[k], s2);
        s3 = fmaf(wreg[3][j][k], hv[k], s3);
      }
    }

    // full-wave DPP reduction (rocPRIM sequence, proven R1/R2); totals -> lane 63
#define DPP_LEVEL(mods) \
    asm("v_add_f32 %0, %0, %0 " mods : "+v"(s0)); \
    asm("v_add_f32 %0, %0, %0 " mods : "+v"(s1)); \
    asm("v_add_f32 %0, %0, %0 " mods : "+v"(s2)); \
    asm("v_add_f32 %0, %0, %0 " mods : "+v"(s3));
    DPP_LEVEL("row_shr:1 bound_ctrl:0")
    DPP_LEVEL("row_shr:2 bound_ctrl:0")
    DPP_LEVEL("row_shr:4 bank_mask:0xe")
    DPP_LEVEL("row_shr:8 bank_mask:0xc")
    DPP_LEVEL("row_bcast:15 row_mask:0xa")
    DPP_LEVEL("row_bcast:31 row_mask:0xc")
#undef DPP_LEVEL

    // gate math PRE-barrier: lane 63 of wave w handles unit u. Runs in
    // parallel across the 8 waves; removes gsum round-trip + post-barrier math.
    if (lane == 63) {
      const float* xb = xgb[t & 1];
      float gi = s0 + xb[w]      + bh0;
      float gf = s1 + xb[8 + w]  + bh1;
      float gg = s2 + xb[16 + w] + bh2;
      float go = s3 + xb[24 + w] + bh3;
      float iv = sigm(gi), fv = sigm(gf), gv = tanh_s(gg), ov = sigm(go);
      c_state = finz(fv * c_state + iv * gv);
      float hval = ov * tanh_s(c_state);
      hpub[w] = hval;
      if (t == 1023) {                 // hs[STRIDE-1], cs[STRIDE-1] (once; uncoalesced OK)
        out[32 + u]       = finz(hval);
        out[32 + HID + u] = finz(c_state);
      }
    }
    __syncthreads();

    // publish: 8 adjacent threads -> ONE coalesced 64B tagged store (R0 pattern).
    // hpub race-free: lane63's next write is after barrier1(t+1), which wave 0
    // only passes after this read (program order).
    if (tid < 8) publish_h(hx, t + 1, g * 8 + tid, hpub[tid]);
  }

  // out[0:32] = tanh(h_fin @ fc_w^T + fc_b): block 0 only
  if (g == 0) {
    float v[2];
    poll2(hx, T_STEPS, j0, v, &alive);
    h_local[j0 + 0] = v[0]; h_local[j0 + 1] = v[1];
    __syncthreads();
    const int m = tid >> 4, seg = tid & 15;   // 32 rows x 16 partials of 64
    float pacc = 0.f;
    for (int k = seg * 64; k < seg * 64 + 64; ++k)
      pacc = fmaf(fcw[m * HID + k], h_local[k], pacc);
    pp[m][seg] = finz(pacc);
    __syncthreads();
    if (tid < 32) {
      float sum = fcb[tid];
      #pragma unroll
      for (int i = 0; i < 16; ++i) sum += pp[tid][i];
      out[tid] = tanh_s(finz(sum));
    }
  }
}

extern "C" void kernel_launch(void* const* d_in, const int* in_sizes, int n_in,
                              void* d_out, int out_size, void* d_ws, size_t ws_size,
                              hipStream_t stream) {
  const float* inp = (const float*)d_in[0];
  const float* h1  = (const float*)d_in[1];
  const float* c1  = (const float*)d_in[2];
  const float* Wih = (const float*)d_in[3];
  const float* Whh = (const float*)d_in[4];
  const float* bih = (const float*)d_in[5];
  const float* bhh = (const float*)d_in[6];
  const float* fcw = (const float*)d_in[7];
  const float* fcb = (const float*)d_in[8];
  float* out = (float*)d_out;

  const size_t xg_bytes  = (size_t)T_STEPS * G4H * 4;             // 33.5 MB
  const size_t hx_bytes  = (size_t)(T_STEPS + 1) * HID * 8;       // 16.8 MB
  const size_t ab_bytes  = (size_t)T_STEPS * K_IN * 2;            // 16.8 MB
  const size_t wb_bytes  = (size_t)G4H * K_IN * 2;                // 33.5 MB
  if (ws_size < xg_bytes + hx_bytes + ab_bytes + wb_bytes) return;

  float* xg   = (float*)d_ws;
  u64*   hx   = (u64*)((char*)d_ws + xg_bytes);
  u16*   Abf  = (u16*)((char*)d_ws + xg_bytes + hx_bytes);
  u16*   Wbf  = (u16*)((char*)d_ws + xg_bytes + hx_bytes + ab_bytes);

  const int nA4 = T_STEPS * K_IN / 4;
  const int nW4 = G4H * K_IN / 4;
  cvt_bf16_k<<<dim3((nA4 + 255) / 256), 256, 0, stream>>>(inp, Abf, nA4);
  cvt_bf16_k<<<dim3((nW4 + 255) / 256), 256, 0, stream>>>(Wih, Wbf, nW4);
  xg_gemm_k<<<dim3(G4H / 128, T_STEPS / 128), 256, 0, stream>>>(Abf, Wbf, bih, xg);
  lstm_scan_k<<<dim3(NWG), 512, 0, stream>>>(Whh, bhh, h1, c1, fcw, fcb, xg, hx, out);
}

// Round 5
// 4747.714 us; speedup vs baseline: 1.6484x; 1.0082x over previous
//
#include <hip/hip_runtime.h>
#include <stdint.h>

typedef unsigned short u16;
typedef unsigned long long u64;
typedef __attribute__((ext_vector_type(8))) short short8;
typedef __attribute__((ext_vector_type(4))) float floatx4;
typedef __attribute__((ext_vector_type(4))) unsigned int u32x4;

#define K_IN    4096   // INPUT_SIZE
#define HID     1024   // HIDDEN
#define G4H     4096   // 4*HIDDEN
#define T_STEPS 2048   // WINDOW
#define NWG     128    // scan workgroups; each owns 8 hidden units
#define SPIN_MAX 60000 // watchdog sweeps; then thread runs free (wrong > hung)

__device__ __forceinline__ u16 f2bf(float f) {
  union { float f; unsigned int i; } v; v.f = f;
  unsigned int lsb = (v.i >> 16) & 1u;
  v.i += 0x7fffu + lsb;
  return (u16)(v.i >> 16);
}
// NaN/Inf -> 0 via INTEGER exponent test: immune to fast-math folding.
__device__ __forceinline__ float finz(float x) {
  unsigned b = __float_as_uint(x);
  return ((b & 0x7f800000u) == 0x7f800000u) ? 0.f : x;
}
__device__ __forceinline__ float sigm(float x) {
  x = fminf(30.f, fmaxf(-30.f, finz(x)));
  return 1.0f / (1.0f + __expf(-x));
}
__device__ __forceinline__ float tanh_s(float x) {
  x = fminf(15.f, fmaxf(-15.f, finz(x)));
  float e = __expf(2.0f * x);
  return (e - 1.0f) / (e + 1.0f);
}

// tagged publish: slot s entry = ((s+1)<<32) | f32bits(h). poison 0xAAAAAAAA never matches.
__device__ __forceinline__ void publish_h(u64* hx, int slot, int idx, float h) {
  h = finz(h);
  u64 v = ((u64)(unsigned)(slot + 1) << 32) | (u64)__float_as_uint(h);
  __hip_atomic_store(&hx[(size_t)slot * HID + idx], v,
                     __ATOMIC_RELAXED, __HIP_MEMORY_SCOPE_AGENT);
}

// poll 2 consecutive entries of slot for tag (slot+1); watchdog -> dead thread.
// R5: ONE fresh global_load_dwordx4 (sc0 sc1 = system-coherent, serves from
// MALL) per sweep instead of two 64b atomic loads -> coherent request rate
// halved at identical structure/freshness/sleep. Tear-safety: each u64 is
// written by one aligned 64b store and read within one 16B cache access;
// tag check only needs per-u64 consistency. A/B history:
//   R2 (3-deep pipelined, no sleep, 3x rate): +370us  -> rate matters
//   R3 (flag gating, extra serial hop): +3000us       -> hops matter more
__device__ __forceinline__ void poll2(const u64* hx, int slot, int j0,
                                      float* v, int* alive) {
  const u64* p = hx + (size_t)slot * HID + j0;   // 16B aligned (j0 even)
  const unsigned tag = (unsigned)(slot + 1);
  if (*alive) {
    int spins = 0;
    for (;;) {
      u32x4 r;
      asm volatile("global_load_dwordx4 %0, %1, off sc0 sc1\n\t"
                   "s_waitcnt vmcnt(0)"
                   : "=&v"(r) : "v"(p) : "memory");
      if (r.y == tag && r.w == tag) {            // hi dwords are the tags
        v[0] = finz(__uint_as_float(r.x));
        v[1] = finz(__uint_as_float(r.z));
        return;
      }
      if (++spins > SPIN_MAX) { *alive = 0; break; }
      __builtin_amdgcn_s_sleep(1);
    }
  }
  v[0] = v[1] = 0.f;
}

// ---------------------------------------------------------------------------
// Phase 0: f32 -> bf16 conversion
// ---------------------------------------------------------------------------
__global__ __launch_bounds__(256) void cvt_bf16_k(const float* __restrict__ src,
                                                  u16* __restrict__ dst, int n4) {
  int i = blockIdx.x * 256 + threadIdx.x;
  if (i < n4) {
    float4 v = *(const float4*)(src + (size_t)i * 4);
    u16 o0 = f2bf(v.x), o1 = f2bf(v.y), o2 = f2bf(v.z), o3 = f2bf(v.w);
    ushort4 o = {o0, o1, o2, o3};
    *(ushort4*)(dst + (size_t)i * 4) = o;
  }
}

// ---------------------------------------------------------------------------
// Phase 1: xg = inp @ W_ih^T + b_ih (f32 out). 128x128 tile, BK=64, bf16 MFMA.
// R5: staging via global_load_lds width-16 (m97 idiom): no VGPR round-trip,
// 4x fewer staging instructions. LDS layout byte-identical to the short8 path
// (dest byte offset = c*16 = wave_base + lane*16). Barrier drains vmcnt.
// ---------------------------------------------------------------------------
#define GLD_LDS16(gsrc, ldst)                                             \
  __builtin_amdgcn_global_load_lds(                                       \
      (const __attribute__((address_space(1))) void*)(gsrc),              \
      (__attribute__((address_space(3))) void*)(ldst), 16, 0, 0)

__global__ __launch_bounds__(256) void xg_gemm_k(const u16* __restrict__ A,      // [2048,4096] bf16
                                                 const u16* __restrict__ B,      // [4096,4096] bf16
                                                 const float* __restrict__ bias, // [4096] f32
                                                 float* __restrict__ C)          // [2048,4096] f32
{
  __shared__ __align__(16) u16 As[128 * 64];
  __shared__ __align__(16) u16 Bs[128 * 64];
  const int tid  = threadIdx.x;
  const int lane = tid & 63;
  const int quad = lane >> 4;
  const int l16  = lane & 15;
  const int wid  = tid >> 6;
  const int wm   = wid >> 1, wn = wid & 1;
  const int tileM = blockIdx.y * 128;
  const int tileN = blockIdx.x * 128;

  floatx4 acc[4][4];
  #pragma unroll
  for (int mi = 0; mi < 4; ++mi)
    #pragma unroll
    for (int ni = 0; ni < 4; ++ni)
      acc[mi][ni] = (floatx4){0.f, 0.f, 0.f, 0.f};

  for (int k0 = 0; k0 < K_IN; k0 += 64) {
    #pragma unroll
    for (int i = 0; i < 4; ++i) {
      int c   = i * 256 + tid;
      int row = c >> 3, col = (c & 7) * 8;
      int cb  = i * 256 + wid * 64;            // wave-uniform dest base (elems/8)
      GLD_LDS16(A + (size_t)(tileM + row) * K_IN + k0 + col, As + (size_t)cb * 8);
      GLD_LDS16(B + (size_t)(tileN + row) * K_IN + k0 + col, Bs + (size_t)cb * 8);
    }
    __syncthreads();   // compiler emits s_waitcnt vmcnt(0) before s_barrier
    #pragma unroll
    for (int kk = 0; kk < 64; kk += 32) {
      short8 av[4], bv[4];
      #pragma unroll
      for (int mi = 0; mi < 4; ++mi)
        av[mi] = *(const short8*)(As + (wm * 64 + mi * 16 + l16) * 64 + kk + quad * 8);
      #pragma unroll
      for (int ni = 0; ni < 4; ++ni)
        bv[ni] = *(const short8*)(Bs + (wn * 64 + ni * 16 + l16) * 64 + kk + quad * 8);
      #pragma unroll
      for (int mi = 0; mi < 4; ++mi)
        #pragma unroll
        for (int ni = 0; ni < 4; ++ni)
          acc[mi][ni] = __builtin_amdgcn_mfma_f32_16x16x32_bf16(av[mi], bv[ni], acc[mi][ni], 0, 0, 0);
    }
    __syncthreads();
  }
  #pragma unroll
  for (int ni = 0; ni < 4; ++ni) {
    int n = tileN + wn * 64 + ni * 16 + l16;
    float bn = bias[n];
    #pragma unroll
    for (int mi = 0; mi < 4; ++mi) {
      int mbase = tileM + wm * 64 + mi * 16 + quad * 4;
      #pragma unroll
      for (int r = 0; r < 4; ++r)
        C[(size_t)(mbase + r) * G4H + n] = acc[mi][ni][r] + bn;
    }
  }
}

// ---------------------------------------------------------------------------
// Phase 2: persistent scan. Communication = R0 skeleton (proven best):
//   512 threads poll2(2 entries, s_sleep) -> stage LDS -> barrier ->
//   dot(b128+DPP) -> lane63 gates pre-barrier -> barrier ->
//   tid<8 ONE coalesced 64B tagged publish. (R4 structure, frozen.)
// ---------------------------------------------------------------------------
__global__ __launch_bounds__(512, 1) void lstm_scan_k(const float* __restrict__ Whh,
                                                      const float* __restrict__ bhh,
                                                      const float* __restrict__ h1,
                                                      const float* __restrict__ c1,
                                                      const float* __restrict__ fcw,
                                                      const float* __restrict__ fcb,
                                                      const float* __restrict__ xg,
                                                      u64* hx,        // [T_STEPS+1][1024]
                                                      float* out)     // [2080] f32
{
  const int g    = blockIdx.x;
  const int tid  = threadIdx.x;
  const int lane = tid & 63;
  const int w    = tid >> 6;           // wave 0..7
  const int u    = g * 8 + w;          // hidden unit owned by this wave

  __shared__ __align__(16) float h_local[HID];
  __shared__ float hpub[8];            // lane63(w) -> hpub[w]; tid<8 publishes
  __shared__ float xgb[2][32];         // parity double-buffer, [q*8 + unit]
  __shared__ float pp[32][16];

  // W_hh rows {u, H+u, 2H+u, 3H+u} -> VGPRs for float4 LDS dot:
  // wreg[q][j][k] multiplies h[j*256 + lane*4 + k]
  floatx4 wreg[4][4];
  #pragma unroll
  for (int q = 0; q < 4; ++q) {
    const float* wr = Whh + (size_t)(q * HID + u) * HID;
    #pragma unroll
    for (int j = 0; j < 4; ++j)
      wreg[q][j] = *(const floatx4*)(wr + j * 256 + lane * 4);
  }
  // per-wave biases (wave-uniform scalar loads)
  const float bh0 = bhh[u], bh1 = bhh[HID + u], bh2 = bhh[2 * HID + u], bh3 = bhh[3 * HID + u];

  float c_state = c1[u];               // evolves meaningfully in lane 63 only
  if (tid < 8) publish_h(hx, 0, g * 8 + tid, h1[g * 8 + tid]);

  int alive = 1;
  const int j0 = tid * 2;              // 512 threads x 2 entries = 1024
  for (int t = 0; t < T_STEPS; ++t) {
    float xval = 0.f;                  // issue xg load before polling
    if (tid < 32) xval = finz(xg[(size_t)t * G4H + (tid >> 3) * HID + g * 8 + (tid & 7)]);
    float v[2];
    poll2(hx, t, j0, v, &alive);
    h_local[j0 + 0] = v[0]; h_local[j0 + 1] = v[1];
    if (tid < 32) xgb[t & 1][tid] = xval;
    __syncthreads();

    // dot: wave w computes the 4 gate rows of unit u via float4 LDS reads
    float s0 = 0.f, s1 = 0.f, s2 = 0.f, s3 = 0.f;
    #pragma unroll
    for (int j = 0; j < 4; ++j) {
      floatx4 hv = *(const floatx4*)(h_local + j * 256 + lane * 4);
      #pragma unroll
      for (int k = 0; k < 4; ++k) {
        s0 = fmaf(wreg[0][j][k], hv[k], s0);
        s1 = fmaf(wreg[1][j][k], hv[k], s1);
        s2 = fmaf(wreg[2][j][k], hv[k], s2);
        s3 = fmaf(wreg[3][j][k], hv[k], s3);
      }
    }

    // full-wave DPP reduction (rocPRIM sequence, proven R1/R2); totals -> lane 63
#define DPP_LEVEL(mods) \
    asm("v_add_f32 %0, %0, %0 " mods : "+v"(s0)); \
    asm("v_add_f32 %0, %0, %0 " mods : "+v"(s1)); \
    asm("v_add_f32 %0, %0, %0 " mods : "+v"(s2)); \
    asm("v_add_f32 %0, %0, %0 " mods : "+v"(s3));
    DPP_LEVEL("row_shr:1 bound_ctrl:0")
    DPP_LEVEL("row_shr:2 bound_ctrl:0")
    DPP_LEVEL("row_shr:4 bank_mask:0xe")
    DPP_LEVEL("row_shr:8 bank_mask:0xc")
    DPP_LEVEL("row_bcast:15 row_mask:0xa")
    DPP_LEVEL("row_bcast:31 row_mask:0xc")
#undef DPP_LEVEL

    // gate math PRE-barrier: lane 63 of wave w handles unit u (parallel across waves)
    if (lane == 63) {
      const float* xb = xgb[t & 1];
      float gi = s0 + xb[w]      + bh0;
      float gf = s1 + xb[8 + w]  + bh1;
      float gg = s2 + xb[16 + w] + bh2;
      float go = s3 + xb[24 + w] + bh3;
      float iv = sigm(gi), fv = sigm(gf), gv = tanh_s(gg), ov = sigm(go);
      c_state = finz(fv * c_state + iv * gv);
      float hval = ov * tanh_s(c_state);
      hpub[w] = hval;
      if (t == 1023) {                 // hs[STRIDE-1], cs[STRIDE-1] (once; uncoalesced OK)
        out[32 + u]       = finz(hval);
        out[32 + HID + u] = finz(c_state);
      }
    }
    __syncthreads();

    // publish: 8 adjacent threads -> ONE coalesced 64B tagged store (R0 pattern).
    if (tid < 8) publish_h(hx, t + 1, g * 8 + tid, hpub[tid]);
  }

  // out[0:32] = tanh(h_fin @ fc_w^T + fc_b): block 0 only
  if (g == 0) {
    float v[2];
    poll2(hx, T_STEPS, j0, v, &alive);
    h_local[j0 + 0] = v[0]; h_local[j0 + 1] = v[1];
    __syncthreads();
    const int m = tid >> 4, seg = tid & 15;   // 32 rows x 16 partials of 64
    float pacc = 0.f;
    for (int k = seg * 64; k < seg * 64 + 64; ++k)
      pacc = fmaf(fcw[m * HID + k], h_local[k], pacc);
    pp[m][seg] = finz(pacc);
    __syncthreads();
    if (tid < 32) {
      float sum = fcb[tid];
      #pragma unroll
      for (int i = 0; i < 16; ++i) sum += pp[tid][i];
      out[tid] = tanh_s(finz(sum));
    }
  }
}

extern "C" void kernel_launch(void* const* d_in, const int* in_sizes, int n_in,
                              void* d_out, int out_size, void* d_ws, size_t ws_size,
                              hipStream_t stream) {
  const float* inp = (const float*)d_in[0];
  const float* h1  = (const float*)d_in[1];
  const float* c1  = (const float*)d_in[2];
  const float* Wih = (const float*)d_in[3];
  const float* Whh = (const float*)d_in[4];
  const float* bih = (const float*)d_in[5];
  const float* bhh = (const float*)d_in[6];
  const float* fcw = (const float*)d_in[7];
  const float* fcb = (const float*)d_in[8];
  float* out = (float*)d_out;

  const size_t xg_bytes  = (size_t)T_STEPS * G4H * 4;             // 33.5 MB
  const size_t hx_bytes  = (size_t)(T_STEPS + 1) * HID * 8;       // 16.8 MB
  const size_t ab_bytes  = (size_t)T_STEPS * K_IN * 2;            // 16.8 MB
  const size_t wb_bytes  = (size_t)G4H * K_IN * 2;                // 33.5 MB
  if (ws_size < xg_bytes + hx_bytes + ab_bytes + wb_bytes) return;

  float* xg   = (float*)d_ws;
  u64*   hx   = (u64*)((char*)d_ws + xg_bytes);
  u16*   Abf  = (u16*)((char*)d_ws + xg_bytes + hx_bytes);
  u16*   Wbf  = (u16*)((char*)d_ws + xg_bytes + hx_bytes + ab_bytes);

  const int nA4 = T_STEPS * K_IN / 4;
  const int nW4 = G4H * K_IN / 4;
  cvt_bf16_k<<<dim3((nA4 + 255) / 256), 256, 0, stream>>>(inp, Abf, nA4);
  cvt_bf16_k<<<dim3((nW4 + 255) / 256), 256, 0, stream>>>(Wih, Wbf, nW4);
  xg_gemm_k<<<dim3(G4H / 128, T_STEPS / 128), 256, 0, stream>>>(Abf, Wbf, bih, xg);
  lstm_scan_k<<<dim3(NWG), 512, 0, stream>>>(Whh, bhh, h1, c1, fcw, fcb, xg, hx, out);
}